// Round 5
// baseline (399.928 us; speedup 1.0000x reference)
//
#include <hip/hip_runtime.h>
#include <stdint.h>

// Problem constants (from reference): B=4, S=4096, D=2, 3 RK2 steps.
#define BATCH   4
#define SEQ     4096
#define WPR     64                  // 64-bit bitmask words per row (SEQ/64)
#define NROWS   (BATCH * SEQ)       // 16384
#define DTS     0.1f
#define HALF_DT 0.05f
#define EPS     1e-8f

// Compress grid: thread-linear streaming, the proven-6.7TB/s access pattern.
#define CB_BLOCKS 2048
#define CB_THR    256
#define CB_WAVES  (CB_BLOCKS * CB_THR / 64)          // 8192 waves
#define TOTAL_CHUNKS (NROWS * 16)                    // 256-float chunks: 262144
#define CHUNKS_PER_WAVE (TOTAL_CHUNKS / CB_WAVES)    // 32

// ---------------------------------------------------------------------------
// Kernel 1: mask -> bitmask, pure streaming. Wave-iteration W loads 64
// contiguous float4 (256 floats, 1 KB, perfectly coalesced). 4 ballots pack
// them into bitmask words 4W..4W+3 (bit j of word 4q+c of row W>>4 is column
// q*256 + 4j + c, q=W&15). Lanes 0-3 store 32 B. ~20 VALU cyc per KB read ->
// BW-bound. No per-row serial tails, no divergent branches, no fusion.
// ---------------------------------------------------------------------------
__global__ __launch_bounds__(CB_THR)
void compress_mask(const float* __restrict__ mask,
                   unsigned long long* __restrict__ bits) {
    const int wid  = (blockIdx.x * CB_THR + threadIdx.x) >> 6;   // 0..8191
    const int lane = threadIdx.x & 63;
    const float4* m4 = reinterpret_cast<const float4*>(mask);

#pragma unroll 8
    for (int it = 0; it < CHUNKS_PER_WAVE; ++it) {
        const int W = wid * CHUNKS_PER_WAVE + it;
        float4 v = m4[(size_t)W * 64 + lane];
        unsigned long long b0 = __ballot(v.x != 0.f);
        unsigned long long b1 = __ballot(v.y != 0.f);
        unsigned long long b2 = __ballot(v.z != 0.f);
        unsigned long long b3 = __ballot(v.w != 0.f);
        unsigned long long w01 = (lane & 1) ? b1 : b0;
        unsigned long long w23 = (lane & 1) ? b3 : b2;
        unsigned long long ws  = (lane & 2) ? w23 : w01;
        if (lane < 4) bits[((size_t)W << 2) + lane] = ws;
    }
}

// ---------------------------------------------------------------------------
// Force + RK2-stage update. Wave-per-row: lane l owns bitmask word l
// (coalesced 512 B/row); bit j of word l -> col = (l>>2)*256 + 4j + (l&3).
// Gathers hit a 32 KB L1-resident batch window; 64-lane xor butterfly.
// Uniform epilogue inputs are hoisted above the gather chain.
// PHASE 0: k1 = M@p - p; star = renorm(p + DT*k1, r);  writes k1,star,r.
// PHASE 1: k2 = M@star - star; p_new = renorm(p + DT/2*(k1+k2), r) -> outbuf.
// ---------------------------------------------------------------------------
template <int PHASE>
__global__ __launch_bounds__(256)
void force_step(const unsigned long long* __restrict__ bits,
                const float2* __restrict__ pIn,     // current state
                const float2* __restrict__ gsrc,    // gather source (p or star)
                float2* __restrict__ k1buf,
                float2* __restrict__ starbuf,
                float*  __restrict__ rbuf,
                float2* __restrict__ outbuf) {
    const int row  = (blockIdx.x * blockDim.x + threadIdx.x) >> 6;
    const int lane = threadIdx.x & 63;
    const int bidx = row >> 12;
    const float2* gb = gsrc + ((size_t)bidx << 12);

    unsigned long long w = bits[(size_t)row * WPR + lane];

    // Hoist wave-uniform epilogue inputs so their latency hides under gathers.
    float2 p = pIn[row];
    float2 st = make_float2(0.f, 0.f), k1v = make_float2(0.f, 0.f);
    float rr = 0.f;
    if (PHASE == 1) { st = gsrc[row]; k1v = k1buf[row]; rr = rbuf[row]; }

    const int colbase = ((lane >> 2) << 8) | (lane & 3);
    float sx = 0.f, sy = 0.f;
    while (w) {
        int j = __builtin_ctzll(w);
        w &= (w - 1);
        float2 v = gb[colbase + (j << 2)];
        sx += v.x; sy += v.y;
    }
#pragma unroll
    for (int m = 32; m >= 1; m >>= 1) {
        sx += __shfl_xor(sx, m, 64);
        sy += __shfl_xor(sy, m, 64);
    }

    if (lane == 0) {
        if (PHASE == 0) {
            float r   = sqrtf(p.x * p.x + p.y * p.y);
            float k1x = sx - p.x, k1y = sy - p.y;
            float tx  = p.x + DTS * k1x, ty = p.y + DTS * k1y;
            float sc  = r / (sqrtf(tx * tx + ty * ty) + EPS);
            k1buf[row]   = make_float2(k1x, k1y);
            starbuf[row] = make_float2(tx * sc, ty * sc);
            rbuf[row]    = r;
        } else {
            float k2x = sx - st.x, k2y = sy - st.y;
            float nx  = p.x + HALF_DT * (k1v.x + k2x);
            float ny  = p.y + HALF_DT * (k1v.y + k2y);
            float sc  = rr / (sqrtf(nx * nx + ny * ny) + EPS);
            outbuf[row] = make_float2(nx * sc, ny * sc);
        }
    }
}

extern "C" void kernel_launch(void* const* d_in, const int* in_sizes, int n_in,
                              void* d_out, int out_size, void* d_ws, size_t ws_size,
                              hipStream_t stream) {
    const float* psi  = (const float*)d_in[0];   // [4,4096,2] fp32
    const float* mask = (const float*)d_in[1];   // [4,4096,4096] fp32 (0/1)
    float2* out2 = (float2*)d_out;               // [4,4096,2] fp32

    // Workspace layout: bitmask 8 MB | p 128 KB | k1 128 KB | star 128 KB | r 64 KB
    char* ws = (char*)d_ws;
    unsigned long long* bits = (unsigned long long*)ws;
    float2* p    = (float2*)(ws + (size_t)NROWS * WPR * 8);
    float2* k1   = p + NROWS;
    float2* star = k1 + NROWS;
    float*  rbuf = (float*)(star + NROWS);

    const float2* psi2 = (const float2*)psi;
    const int fgrid = NROWS / 4;                 // 4 waves (rows) per 256-thr block

    compress_mask<<<CB_BLOCKS, CB_THR, 0, stream>>>(mask, bits);

    // step 1 (reads psi from d_in, writes p into ws)
    force_step<0><<<fgrid, 256, 0, stream>>>(bits, psi2, psi2, k1, star, rbuf, nullptr);
    force_step<1><<<fgrid, 256, 0, stream>>>(bits, psi2, star, k1, star, rbuf, p);
    // step 2 (in-place p update; PHASE 1 only reads its own p[row])
    force_step<0><<<fgrid, 256, 0, stream>>>(bits, p, p, k1, star, rbuf, nullptr);
    force_step<1><<<fgrid, 256, 0, stream>>>(bits, p, star, k1, star, rbuf, p);
    // step 3 (writes final state straight to d_out)
    force_step<0><<<fgrid, 256, 0, stream>>>(bits, p, p, k1, star, rbuf, nullptr);
    force_step<1><<<fgrid, 256, 0, stream>>>(bits, p, star, k1, star, rbuf, out2);
}